// Round 19
// baseline (140.055 us; speedup 1.0000x reference)
//
#include <hip/hip_runtime.h>
#include <math.h>

#define NB 32
#define ND 768
#define NS 196
#define NL 77

typedef _Float16 f16x8 __attribute__((ext_vector_type(8)));
typedef float f32x4 __attribute__((ext_vector_type(4)));

__device__ __forceinline__ f32x4 mfma16(f16x8 a, f16x8 b, f32x4 c) {
  return __builtin_amdgcn_mfma_f32_16x16x32_f16(a, b, c, 0, 0, 0);
}

#define GLOAD16(gp, lp)                                          \
  __builtin_amdgcn_global_load_lds(                              \
      (const __attribute__((address_space(1))) void*)(gp),       \
      (__attribute__((address_space(3))) void*)(lp), 16, 0, 0)

// Workspace (f16 elems):
//   txf: [i][24 dk][5 lt][512]  = 1,966,080   (B operand, single fp16)
//   cTf: [j][13 S][24 dk][512]  = 5,111,808   (A operand, single fp16)
//   Gf : [j][13 S][7 kt][512]   = 1,490,944   (Gram, single fp16)

// ===================== prep_all: tx-fragments | ctx->frag transpose | lens+word-norms =====================
__global__ __launch_bounds__(256) void prep_all_kernel(
    const float* __restrict__ text_local,
    const float* __restrict__ img_local,
    const int* __restrict__ amask,
    _Float16* __restrict__ txf, _Float16* __restrict__ cTf,
    float* __restrict__ n1ws, int* __restrict__ lenws) {
  const int bid = blockIdx.x;
  const int t = threadIdx.x;
  __shared__ float tile[32][213];  // 27.3 KB transpose staging

  if (bid < 960) {
    // ---- text fragments: txf[i][dk][lt][512], single fp16 ----
    int tau = bid * 256 + t;            // 32*24*5*64
    int i = tau / 7680;
    int r = tau - i * 7680;
    int dk = r / 320;
    int r2 = r - dk * 320;
    int lt = r2 >> 6, lane = r2 & 63;
    int n16 = lane & 15, g = lane >> 4;
    int l = lt * 16 + n16;
    float v[8];
#pragma unroll
    for (int q = 0; q < 8; ++q) v[q] = 0.f;
    if (l < NL) {
      const float* src = text_local + ((size_t)i * NL + l) * ND + dk * 32 + g * 8;
      float4 a = *(const float4*)src;
      float4 b = *(const float4*)(src + 4);
      v[0] = a.x; v[1] = a.y; v[2] = a.z; v[3] = a.w;
      v[4] = b.x; v[5] = b.y; v[6] = b.z; v[7] = b.w;
    }
    f16x8 hv;
#pragma unroll
    for (int q = 0; q < 8; ++q) hv[q] = (_Float16)v[q];
    size_t base = (((size_t)i * 24 + dk) * 5 + lt) * 512 + (size_t)lane * 8;
    *(f16x8*)(txf + base) = hv;
  } else if (bid < 1344) {
    // ---- ctx transpose to fragment layout cTf[j][S][dk][512], single fp16 ----
    const int b2 = bid - 960;
    const int j = b2 / 12, dc = b2 - (b2 / 12) * 12;  // dc covers dk {2dc, 2dc+1}
    const float* src = img_local + ((size_t)j * ND + dc * 64) * NS;
#pragma unroll 1
    for (int h = 0; h < 2; ++h) {
      __syncthreads();
      for (int idx = t; idx < 1568; idx += 256) {  // 32 d-rows * 49 float4
        int dd = idx / 49, sq = idx - dd * 49;
        float4 v = *(const float4*)(src + (size_t)(h * 32 + dd) * NS + sq * 4);
        tile[dd][sq * 4 + 0] = v.x;
        tile[dd][sq * 4 + 1] = v.y;
        tile[dd][sq * 4 + 2] = v.z;
        tile[dd][sq * 4 + 3] = v.w;
      }
      __syncthreads();
      const int dk = dc * 2 + h;
      for (int idx = t; idx < 832; idx += 256) {  // 13 S * 64 lanes
        int lane = idx & 63;
        int S = idx >> 6;
        int n16 = lane & 15, g = lane >> 4;
        int s = S * 16 + n16;
        f16x8 hv;
#pragma unroll
        for (int e = 0; e < 8; ++e) {
          float v = (s < NS) ? tile[g * 8 + e][s] : 0.f;
          hv[e] = (_Float16)v;
        }
        size_t base = (((size_t)j * 13 + S) * 24 + dk) * 512 + (size_t)lane * 8;
        *(f16x8*)(cTf + base) = hv;
      }
    }
  } else {
    // ---- lengths + word norms ----
    const int i = bid - 1344;
    const int lane = t & 63, w = t >> 6;
    __shared__ int slen;
    if (t == 0) slen = 0;
    __syncthreads();
    if (t < NL && amask[i * NL + t] != 0) atomicAdd(&slen, 1);
    for (int l = w; l < NL; l += 4) {
      const float4* p = (const float4*)(text_local + ((size_t)i * NL + l) * ND);
      float s = 0.f;
#pragma unroll
      for (int k = 0; k < 3; ++k) {
        float4 v = p[lane + 64 * k];
        s += v.x * v.x + v.y * v.y + v.z * v.z + v.w * v.w;
      }
#pragma unroll
      for (int off = 32; off; off >>= 1) s += __shfl_xor(s, off);
      if (lane == 0) n1ws[i * 80 + l] = sqrtf(s);
    }
    __syncthreads();
    if (t == 0) lenws[i] = slen;
  }
}

// ===================== mid: Gram (fp16 single in/out) | global scores | len-sorted order =====================
__global__ void mid_kernel(const _Float16* __restrict__ cTf, _Float16* __restrict__ Gf,
                           const float* __restrict__ img_global,
                           const float* __restrict__ text_global,
                           float* __restrict__ gscw,
                           const int* __restrict__ lenws, int* __restrict__ ordws) {
  const int bid = blockIdx.x;
  const int t = threadIdx.x;
  __shared__ __align__(16) float shi[ND];

  if (bid < 832) {
    // ---- Gram ----
    const int j = bid / 26;
    const int rr = bid - j * 26;
    const int st = rr >> 1, ch = rr & 1;
    const int lane = t & 63, w = t >> 6;
    const int g = lane >> 4, n16 = lane & 15;
    const f32x4 z4 = {0.f, 0.f, 0.f, 0.f};
    f32x4 accG[2];
    accG[0] = z4; accG[1] = z4;
    const int base = ch * 7;
    const int ncols = ch ? 6 : 7;
    const size_t cj = (size_t)j * 13;
    for (int dk = 0; dk < 24; ++dk) {
      size_t ao = ((cj + st) * 24 + dk) * 512 + (size_t)lane * 8;
      f16x8 A = *(const f16x8*)(cTf + ao);
#pragma unroll
      for (int q = 0; q < 2; ++q) {
        int ntl = w + (q << 2);
        if (ntl < ncols) {
          int nt = base + ntl;
          size_t bo = ((cj + nt) * 24 + dk) * 512 + (size_t)lane * 8;
          f16x8 B = *(const f16x8*)(cTf + bo);
          accG[q] = mfma16(A, B, accG[q]);
        }
      }
    }
#pragma unroll
    for (int q = 0; q < 2; ++q) {
      int ntl = w + (q << 2);
      int nt = base + ntl;
      bool compute = (ntl < ncols);
      bool zfill = (ch == 1 && nt == 13);
      if (compute || zfill) {
#pragma unroll
        for (int r = 0; r < 4; ++r) {
          int col = nt * 16 + n16;
          float v = compute ? accG[q][r] : 0.f;
          int kt = col >> 5, gg = (col >> 3) & 3, e = col & 7;
          int lane2 = (g * 4 + r) + (gg << 4);
          size_t o = (((size_t)j * 13 + st) * 7 + kt) * 512 + (size_t)lane2 * 8 + e;
          Gf[o] = (_Float16)v;
        }
      }
    }
  } else if (bid < 864) {
    // ---- global contrastive scores ----
    const int a = bid - 832;
    const int lane = t & 63, w = t >> 6;
    if (t < ND / 4) ((float4*)shi)[t] = ((const float4*)(img_global + (size_t)a * ND))[t];
    __syncthreads();
    for (int b = w; b < NB; b += 4) {
      const float4* pt = (const float4*)(text_global + (size_t)b * ND);
      const float4* pi = (const float4*)shi;
      float dot = 0.f, ni = 0.f, nt = 0.f;
#pragma unroll
      for (int k = 0; k < 3; ++k) {
        float4 x = pi[lane + 64 * k];
        float4 y = pt[lane + 64 * k];
        dot += x.x * y.x + x.y * y.y + x.z * y.z + x.w * y.w;
        ni  += x.x * x.x + x.y * x.y + x.z * x.z + x.w * x.w;
        nt  += y.x * y.x + y.y * y.y + y.z * y.z + y.w * y.w;
      }
#pragma unroll
      for (int off = 32; off; off >>= 1) {
        dot += __shfl_xor(dot, off);
        ni  += __shfl_xor(ni, off);
        nt  += __shfl_xor(nt, off);
      }
      if (lane == 0)
        gscw[a * NB + b] = dot / fmaxf(sqrtf(ni), 1e-12f) / fmaxf(sqrtf(nt), 1e-12f) * 10.0f;
    }
  } else {
    // ---- sorted order (desc by len), deterministic ----
    if (t == 0) {
      int o[32];
      for (int k = 0; k < 32; ++k) o[k] = k;
      for (int x = 0; x < 31; ++x) {
        int best = x;
        for (int y = x + 1; y < 32; ++y)
          if (lenws[o[y]] > lenws[o[best]]) best = y;
        int tmp = o[x]; o[x] = o[best]; o[best] = tmp;
      }
      for (int k = 0; k < 32; ++k) ordws[k] = o[k];
    }
  }
}

// ===================== pair kernel: 16 waves, 2 complementary pairs, 1 S-tile/wave, 2-dk/barrier =====================
__global__ __launch_bounds__(1024, 2) void pair_kernel(
    const _Float16* __restrict__ txf, const _Float16* __restrict__ cTf,
    const _Float16* __restrict__ Gf,
    const float* __restrict__ n1ws, const int* __restrict__ lenws,
    const int* __restrict__ ordws,
    float* __restrict__ simws) {
  const int t = threadIdx.x;
  // XCD swizzle: 512 % 8 == 0 -> bijective
  const int wg = ((blockIdx.x & 7) << 6) + (blockIdx.x >> 3);
  const int j = wg >> 4;
  const int m = wg & 15;
  const int i0 = ordws[m], i1 = ordws[31 - m];   // complementary lens -> ~constant work
  const int len0 = lenws[i0], len1 = lenws[i1];
  const int nlt0 = (len0 + 15) >> 4, nlt1 = (len1 + 15) >> 4;
  const int lane = t & 63, wid = t >> 6;           // wid 0..15
  const int g = lane >> 4, n16 = lane & 15;
  const bool va = (wid < 13);                      // this wave owns S-tile wid

  __shared__ __align__(16) union {
    _Float16 e2f[7 * 5 * 64 * 8];          // 35840 B (phases 2-3, per pair sequentially)
    _Float16 b1[2][2][2][5][512];          // 40960 B: [dbuf][dk-in-pair][i][lt][512]
  } U;
  __shared__ float w12s[80], z2s[80], n2s[80];

  const f32x4 z4 = {0.f, 0.f, 0.f, 0.f};
  f32x4 acc[2][5];  // [pair][lt] -- single S-tile per wave, statically indexed
#pragma unroll
  for (int p = 0; p < 2; ++p)
#pragma unroll
    for (int lt = 0; lt < 5; ++lt) acc[p][lt] = z4;

  const _Float16* txi0 = txf + (size_t)i0 * 24 * 5 * 512;
  const _Float16* txi1 = txf + (size_t)i1 * 24 * 5 * 512;
  const size_t cj = (size_t)j * 13;

  // staging: 20 chunks/iter (2 dk x 2 i x 5 lt) over 16 waves, exact coverage
#define STAGE(BUF, DKBASE)                                                       \
  do {                                                                           \
    _Pragma("unroll")                                                            \
    for (int k = 0; k < 2; ++k) {                                                \
      int slot = wid + (k << 4);                                                 \
      if (slot < 20) {                                                           \
        int d = slot / 10, rem = slot - d * 10;                                  \
        int ii = rem / 5, lt = rem - ii * 5;                                     \
        const _Float16* tx = ii ? txi1 : txi0;                                   \
        GLOAD16(tx + ((size_t)(((DKBASE) + d) * 5 + lt) << 9) + ((size_t)lane << 3), \
                &U.b1[BUF][d][ii][lt][0]);                                       \
      }                                                                          \
    }                                                                            \
  } while (0)

  // ---- prologue: stage dk 0,1 ----
  STAGE(0, 0);
  __syncthreads();

  // ---- phase 1: logits for BOTH pairs; 2 dk per barrier iteration, 1 S-tile/wave ----
#pragma unroll 1
  for (int dkp = 0; dkp < 12; ++dkp) {
    const int cur = dkp & 1;
    const int dk0 = dkp * 2;
    f16x8 Aa0, Aa1;
    if (va) {
      size_t ao = ((cj + wid) * 24 + dk0) * 512 + ((size_t)lane << 3);
      Aa0 = *(const f16x8*)(cTf + ao);
      Aa1 = *(const f16x8*)(cTf + ao + 512);
    }
    if (dkp < 11) STAGE(cur ^ 1, dk0 + 2);
    __builtin_amdgcn_s_setprio(1);
    if (va) {
#pragma unroll
      for (int lt = 0; lt < 5; ++lt) {
        if (lt < nlt0) {
          f16x8 B0 = *(const f16x8*)&U.b1[cur][0][0][lt][lane << 3];
          acc[0][lt] = mfma16(Aa0, B0, acc[0][lt]);
        }
        if (lt < nlt1) {
          f16x8 B1 = *(const f16x8*)&U.b1[cur][0][1][lt][lane << 3];
          acc[1][lt] = mfma16(Aa0, B1, acc[1][lt]);
        }
      }
#pragma unroll
      for (int lt = 0; lt < 5; ++lt) {
        if (lt < nlt0) {
          f16x8 B0 = *(const f16x8*)&U.b1[cur][1][0][lt][lane << 3];
          acc[0][lt] = mfma16(Aa1, B0, acc[0][lt]);
        }
        if (lt < nlt1) {
          f16x8 B1 = *(const f16x8*)&U.b1[cur][1][1][lt][lane << 3];
          acc[1][lt] = mfma16(Aa1, B1, acc[1][lt]);
        }
      }
    }
    __builtin_amdgcn_s_setprio(0);
    __syncthreads();
  }

  // ---- phases 2+3+epilogue per pair, sequentially (shared e2f/w12s buffers) ----
#pragma unroll
  for (int p = 0; p < 2; ++p) {
    const int ip   = p ? i1 : i0;
    const int lenp = p ? len1 : len0;
    const int nltp = p ? nlt1 : nlt0;

    __syncthreads();  // protect previous pair's buffers
    if (t < 80) { w12s[t] = 0.f; z2s[t] = 0.f; n2s[t] = 0.f; }
    for (int idx = t; idx < 2240; idx += 1024)
      ((uint4*)U.e2f)[idx] = make_uint4(0, 0, 0, 0);
    __syncthreads();

    // ---- phase 2: register softmax over l, e2 = exp(4*a1), fold w12/Z2 ----
    float w12loc[5], z2loc[5];
#pragma unroll
    for (int lt = 0; lt < 5; ++lt) { w12loc[lt] = 0.f; z2loc[lt] = 0.f; }
    if (va) {
      const int S = wid;
#pragma unroll
      for (int r = 0; r < 4; ++r) {
        int s = S * 16 + g * 4 + r;
        bool srow = (s < NS);
        float mx = -1e30f;
#pragma unroll
        for (int lt = 0; lt < 5; ++lt) {
          if (lt < nltp) {
            if ((lt * 16 + n16) < lenp) mx = fmaxf(mx, acc[p][lt][r]);
          }
        }
        mx = fmaxf(mx, __shfl_xor(mx, 1));
        mx = fmaxf(mx, __shfl_xor(mx, 2));
        mx = fmaxf(mx, __shfl_xor(mx, 4));
        mx = fmaxf(mx, __shfl_xor(mx, 8));
        float z = 0.f;
        float ev[5];
#pragma unroll
        for (int lt = 0; lt < 5; ++lt) {
          float e = 0.f;
          if (lt < nltp) {
            if ((lt * 16 + n16) < lenp) e = __expf(acc[p][lt][r] - mx);
          }
          ev[lt] = e;
          z += e;
        }
        z += __shfl_xor(z, 1);
        z += __shfl_xor(z, 2);
        z += __shfl_xor(z, 4);
        z += __shfl_xor(z, 8);
        float inv = 4.0f / z;
#pragma unroll
        for (int lt = 0; lt < 5; ++lt) {
          if (lt < nltp) {
            if (((lt * 16 + n16) < lenp) && srow) {
              float e2 = __expf(ev[lt] * inv);
              w12loc[lt] += e2 * acc[p][lt][r];
              z2loc[lt] += e2;
              int kt = s >> 5, kk = s & 31;
              U.e2f[(((kt * 5) + lt) * 64 + (n16 + ((kk >> 3) << 4))) * 8 + (kk & 7)] = (_Float16)e2;
            }
          }
        }
      }
    }
#pragma unroll
    for (int lt = 0; lt < 5; ++lt) {
      w12loc[lt] += __shfl_xor(w12loc[lt], 16);
      w12loc[lt] += __shfl_xor(w12loc[lt], 32);
      z2loc[lt] += __shfl_xor(z2loc[lt], 16);
      z2loc[lt] += __shfl_xor(z2loc[lt], 32);
    }
    if (va && lane < 16) {
#pragma unroll
      for (int lt = 0; lt < 5; ++lt) {
        if (lt < nltp) {
          atomicAdd(&w12s[lt * 16 + lane], w12loc[lt]);
          atomicAdd(&z2s[lt * 16 + lane], z2loc[lt]);
        }
      }
    }
    __syncthreads();  // e2f complete

    // ---- phase 3: n2^2 = e2^T G e2 via MFMA, single-plane fp16 Gf + kt-prefetch ----
    float n2loc[5];
#pragma unroll
    for (int lt = 0; lt < 5; ++lt) n2loc[lt] = 0.f;
    if (va) {
      const int S = wid;
      f32x4 a2[5];
#pragma unroll
      for (int lt = 0; lt < 5; ++lt) a2[lt] = z4;
      const _Float16* gp = Gf + (((size_t)j * 13 + S) * 7) * 512 + ((size_t)lane << 3);
      f16x8 GA = *(const f16x8*)gp;
#pragma unroll
      for (int kt = 0; kt < 7; ++kt) {
        f16x8 GAN;
        if (kt < 6) GAN = *(const f16x8*)(gp + (size_t)(kt + 1) * 512);
        __builtin_amdgcn_s_setprio(1);
#pragma unroll
        for (int lt = 0; lt < 5; ++lt) {
          if (lt < nltp) {
            f16x8 Bv = *(const f16x8*)&U.e2f[(((kt * 5) + lt) * 64 + lane) * 8];
            a2[lt] = mfma16(GA, Bv, a2[lt]);
          }
        }
        __builtin_amdgcn_s_setprio(0);
        if (kt < 6) GA = GAN;
      }
#pragma unroll
      for (int lt = 0; lt < 5; ++lt) {
        if (lt < nltp) {
#pragma unroll
          for (int r = 0; r < 4; ++r) {
            int s = S * 16 + g * 4 + r;
            int kt = s >> 5, kk = s & 31;
            float e2v = (float)U.e2f[(((kt * 5) + lt) * 64 + (n16 + ((kk >> 3) << 4))) * 8 + (kk & 7)];
            n2loc[lt] += e2v * a2[lt][r];
          }
        }
      }
    }
#pragma unroll
    for (int lt = 0; lt < 5; ++lt) {
      n2loc[lt] += __shfl_xor(n2loc[lt], 16);
      n2loc[lt] += __shfl_xor(n2loc[lt], 32);
    }
    if (va && lane < 16) {
#pragma unroll
      for (int lt = 0; lt < 5; ++lt) {
        if (lt < nltp) atomicAdd(&n2s[lt * 16 + lane], n2loc[lt]);
      }
    }
    __syncthreads();

    // ---- epilogue: cosine + exp, wave-parallel log-sum ----
    if (t < lenp) {
      float z2 = z2s[t];
      float w12v = w12s[t] / z2;
      float n2v = sqrtf(n2s[t]) / z2;
      float n1v = n1ws[ip * 80 + t];
      float cosv = w12v / fmaxf(n1v * n2v, 1e-8f);
      w12s[t] = __expf(5.0f * cosv);
    }
    __syncthreads();
    if (wid == 0) {
      float e = (lane < lenp) ? w12s[lane] : 0.f;
      if (lane + 64 < lenp) e += w12s[lane + 64];
      e += __shfl_xor(e, 1);
      e += __shfl_xor(e, 2);
      e += __shfl_xor(e, 4);
      e += __shfl_xor(e, 8);
      e += __shfl_xor(e, 16);
      e += __shfl_xor(e, 32);
      if (lane == 0) simws[ip * NB + j] = __logf(e);
    }
  }
#undef STAGE
}

// ===================== final cross-entropies =====================
__global__ void loss_kernel(const float* __restrict__ gscw,
                            const float* __restrict__ simws,
                            float* __restrict__ out) {
  const int t = threadIdx.x;
  __shared__ float gs[NB][NB];
  __shared__ float sl[NB][NB];
  __shared__ float parts[4][NB];
  {
    float4 gv = ((const float4*)gscw)[t];
    ((float4*)gs)[t] = gv;
    float4 v = ((const float4*)simws)[t];
    int ii = t >> 3;
    int j0 = (t & 7) * 4;
    sl[j0 + 0][ii] = v.x * 10.0f;
    sl[j0 + 1][ii] = v.y * 10.0f;
    sl[j0 + 2][ii] = v.z * 10.0f;
    sl[j0 + 3][ii] = v.w * 10.0f;
  }
  __syncthreads();
  if (t < NB) {
    float m, z;
    m = -1e30f;
    for (int c = 0; c < NB; ++c) m = fmaxf(m, gs[t][c]);
    z = 0.f;
    for (int c = 0; c < NB; ++c) z += __expf(gs[t][c] - m);
    parts[0][t] = m + __logf(z) - gs[t][t];

    m = -1e30f;
    for (int c = 0; c < NB; ++c) m = fmaxf(m, gs[c][t]);
    z = 0.f;
    for (int c = 0; c < NB; ++c) z += __expf(gs[c][t] - m);
    parts[1][t] = m + __logf(z) - gs[t][t];

    m = -1e30f;
    for (int c = 0; c < NB; ++c) m = fmaxf(m, sl[t][c]);
    z = 0.f;
    for (int c = 0; c < NB; ++c) z += __expf(sl[t][c] - m);
    parts[2][t] = m + __logf(z) - sl[t][t];

    m = -1e30f;
    for (int c = 0; c < NB; ++c) m = fmaxf(m, sl[c][t]);
    z = 0.f;
    for (int c = 0; c < NB; ++c) z += __expf(sl[c][t] - m);
    parts[3][t] = m + __logf(z) - sl[t][t];
  }
  __syncthreads();
  if (t == 0) {
    float s0 = 0.f, s1 = 0.f, s2 = 0.f, s3 = 0.f;
    for (int r = 0; r < NB; ++r) {
      s0 += parts[0][r]; s1 += parts[1][r];
      s2 += parts[2][r]; s3 += parts[3][r];
    }
    out[0] = 0.5f * (s0 + s1) / 32.0f + 0.5f * (s2 + s3) / 32.0f;
  }
}

extern "C" void kernel_launch(void* const* d_in, const int* in_sizes, int n_in,
                              void* d_out, int out_size, void* d_ws, size_t ws_size,
                              hipStream_t stream) {
  (void)in_sizes; (void)n_in; (void)out_size; (void)ws_size;
  const float* img_global  = (const float*)d_in[0];
  const float* img_local   = (const float*)d_in[1];
  const float* text_global = (const float*)d_in[2];
  const float* text_local  = (const float*)d_in[3];
  const int*   amask       = (const int*)d_in[4];

  _Float16* txf = (_Float16*)d_ws;                // 1,966,080
  _Float16* cTf = txf + (size_t)1966080;          // 5,111,808
  _Float16* Gf  = cTf + (size_t)5111808;          // 1,490,944
  float* fsm  = (float*)(Gf + (size_t)1490944);
  float* n1ws  = fsm;                              // [32][80]
  float* simws = fsm + 2560;                       // [32][32]
  float* gscw  = fsm + 3584;                       // [32][32]
  int*   lenws = (int*)(fsm + 4608);               // [32]
  int*   ordws = (int*)(fsm + 4640);               // [32]

  prep_all_kernel<<<1376, 256, 0, stream>>>(text_local, img_local, amask,
                                            txf, cTf, n1ws, lenws);
  mid_kernel<<<865, 256, 0, stream>>>(cTf, Gf, img_global, text_global,
                                      gscw, lenws, ordws);
  pair_kernel<<<512, 1024, 0, stream>>>(txf, cTf, Gf, n1ws, lenws, ordws, simws);
  loss_kernel<<<1, 256, 0, stream>>>(gscw, simws, (float*)d_out);
}

// Round 20
// 118.346 us; speedup vs baseline: 1.1834x; 1.1834x over previous
//
#include <hip/hip_runtime.h>
#include <math.h>

#define NB 32
#define ND 768
#define NS 196
#define NL 77

typedef _Float16 f16x8 __attribute__((ext_vector_type(8)));
typedef float f32x4 __attribute__((ext_vector_type(4)));

__device__ __forceinline__ f32x4 mfma16(f16x8 a, f16x8 b, f32x4 c) {
  return __builtin_amdgcn_mfma_f32_16x16x32_f16(a, b, c, 0, 0, 0);
}

#define GLOAD16(gp, lp)                                          \
  __builtin_amdgcn_global_load_lds(                              \
      (const __attribute__((address_space(1))) void*)(gp),       \
      (__attribute__((address_space(3))) void*)(lp), 16, 0, 0)

// Workspace (f16 elems):
//   txf: [i][24 dk][5 lt][512]  = 1,966,080   (B operand, single fp16)
//   cTf: [j][13 S][24 dk][512]  = 5,111,808   (A operand, single fp16)
//   Gf : [j][13 S][7 kt][512]   = 1,490,944   (Gram, single fp16)

// ===================== prep_all: tx-fragments | ctx->frag transpose | lens+word-norms =====================
__global__ __launch_bounds__(256) void prep_all_kernel(
    const float* __restrict__ text_local,
    const float* __restrict__ img_local,
    const int* __restrict__ amask,
    _Float16* __restrict__ txf, _Float16* __restrict__ cTf,
    float* __restrict__ n1ws, int* __restrict__ lenws) {
  const int bid = blockIdx.x;
  const int t = threadIdx.x;
  __shared__ float tile[32][213];  // 27.3 KB transpose staging

  if (bid < 960) {
    // ---- text fragments: txf[i][dk][lt][512], single fp16 ----
    int tau = bid * 256 + t;            // 32*24*5*64
    int i = tau / 7680;
    int r = tau - i * 7680;
    int dk = r / 320;
    int r2 = r - dk * 320;
    int lt = r2 >> 6, lane = r2 & 63;
    int n16 = lane & 15, g = lane >> 4;
    int l = lt * 16 + n16;
    float v[8];
#pragma unroll
    for (int q = 0; q < 8; ++q) v[q] = 0.f;
    if (l < NL) {
      const float* src = text_local + ((size_t)i * NL + l) * ND + dk * 32 + g * 8;
      float4 a = *(const float4*)src;
      float4 b = *(const float4*)(src + 4);
      v[0] = a.x; v[1] = a.y; v[2] = a.z; v[3] = a.w;
      v[4] = b.x; v[5] = b.y; v[6] = b.z; v[7] = b.w;
    }
    f16x8 hv;
#pragma unroll
    for (int q = 0; q < 8; ++q) hv[q] = (_Float16)v[q];
    size_t base = (((size_t)i * 24 + dk) * 5 + lt) * 512 + (size_t)lane * 8;
    *(f16x8*)(txf + base) = hv;
  } else if (bid < 1344) {
    // ---- ctx transpose to fragment layout cTf[j][S][dk][512], single fp16 ----
    const int b2 = bid - 960;
    const int j = b2 / 12, dc = b2 - (b2 / 12) * 12;  // dc covers dk {2dc, 2dc+1}
    const float* src = img_local + ((size_t)j * ND + dc * 64) * NS;
#pragma unroll 1
    for (int h = 0; h < 2; ++h) {
      __syncthreads();
      for (int idx = t; idx < 1568; idx += 256) {  // 32 d-rows * 49 float4
        int dd = idx / 49, sq = idx - dd * 49;
        float4 v = *(const float4*)(src + (size_t)(h * 32 + dd) * NS + sq * 4);
        tile[dd][sq * 4 + 0] = v.x;
        tile[dd][sq * 4 + 1] = v.y;
        tile[dd][sq * 4 + 2] = v.z;
        tile[dd][sq * 4 + 3] = v.w;
      }
      __syncthreads();
      const int dk = dc * 2 + h;
      for (int idx = t; idx < 832; idx += 256) {  // 13 S * 64 lanes
        int lane = idx & 63;
        int S = idx >> 6;
        int n16 = lane & 15, g = lane >> 4;
        int s = S * 16 + n16;
        f16x8 hv;
#pragma unroll
        for (int e = 0; e < 8; ++e) {
          float v = (s < NS) ? tile[g * 8 + e][s] : 0.f;
          hv[e] = (_Float16)v;
        }
        size_t base = (((size_t)j * 13 + S) * 24 + dk) * 512 + (size_t)lane * 8;
        *(f16x8*)(cTf + base) = hv;
      }
    }
  } else {
    // ---- lengths + word norms ----
    const int i = bid - 1344;
    const int lane = t & 63, w = t >> 6;
    __shared__ int slen;
    if (t == 0) slen = 0;
    __syncthreads();
    if (t < NL && amask[i * NL + t] != 0) atomicAdd(&slen, 1);
    for (int l = w; l < NL; l += 4) {
      const float4* p = (const float4*)(text_local + ((size_t)i * NL + l) * ND);
      float s = 0.f;
#pragma unroll
      for (int k = 0; k < 3; ++k) {
        float4 v = p[lane + 64 * k];
        s += v.x * v.x + v.y * v.y + v.z * v.z + v.w * v.w;
      }
#pragma unroll
      for (int off = 32; off; off >>= 1) s += __shfl_xor(s, off);
      if (lane == 0) n1ws[i * 80 + l] = sqrtf(s);
    }
    __syncthreads();
    if (t == 0) lenws[i] = slen;
  }
}

// ===================== mid: Gram (fp16 single in/out) | global scores | len-sorted order =====================
__global__ void mid_kernel(const _Float16* __restrict__ cTf, _Float16* __restrict__ Gf,
                           const float* __restrict__ img_global,
                           const float* __restrict__ text_global,
                           float* __restrict__ gscw,
                           const int* __restrict__ lenws, int* __restrict__ ordws) {
  const int bid = blockIdx.x;
  const int t = threadIdx.x;
  __shared__ __align__(16) float shi[ND];

  if (bid < 832) {
    // ---- Gram ----
    const int j = bid / 26;
    const int rr = bid - j * 26;
    const int st = rr >> 1, ch = rr & 1;
    const int lane = t & 63, w = t >> 6;
    const int g = lane >> 4, n16 = lane & 15;
    const f32x4 z4 = {0.f, 0.f, 0.f, 0.f};
    f32x4 accG[2];
    accG[0] = z4; accG[1] = z4;
    const int base = ch * 7;
    const int ncols = ch ? 6 : 7;
    const size_t cj = (size_t)j * 13;
    for (int dk = 0; dk < 24; ++dk) {
      size_t ao = ((cj + st) * 24 + dk) * 512 + (size_t)lane * 8;
      f16x8 A = *(const f16x8*)(cTf + ao);
#pragma unroll
      for (int q = 0; q < 2; ++q) {
        int ntl = w + (q << 2);
        if (ntl < ncols) {
          int nt = base + ntl;
          size_t bo = ((cj + nt) * 24 + dk) * 512 + (size_t)lane * 8;
          f16x8 B = *(const f16x8*)(cTf + bo);
          accG[q] = mfma16(A, B, accG[q]);
        }
      }
    }
#pragma unroll
    for (int q = 0; q < 2; ++q) {
      int ntl = w + (q << 2);
      int nt = base + ntl;
      bool compute = (ntl < ncols);
      bool zfill = (ch == 1 && nt == 13);
      if (compute || zfill) {
#pragma unroll
        for (int r = 0; r < 4; ++r) {
          int col = nt * 16 + n16;
          float v = compute ? accG[q][r] : 0.f;
          int kt = col >> 5, gg = (col >> 3) & 3, e = col & 7;
          int lane2 = (g * 4 + r) + (gg << 4);
          size_t o = (((size_t)j * 13 + st) * 7 + kt) * 512 + (size_t)lane2 * 8 + e;
          Gf[o] = (_Float16)v;
        }
      }
    }
  } else if (bid < 864) {
    // ---- global contrastive scores ----
    const int a = bid - 832;
    const int lane = t & 63, w = t >> 6;
    if (t < ND / 4) ((float4*)shi)[t] = ((const float4*)(img_global + (size_t)a * ND))[t];
    __syncthreads();
    for (int b = w; b < NB; b += 4) {
      const float4* pt = (const float4*)(text_global + (size_t)b * ND);
      const float4* pi = (const float4*)shi;
      float dot = 0.f, ni = 0.f, nt = 0.f;
#pragma unroll
      for (int k = 0; k < 3; ++k) {
        float4 x = pi[lane + 64 * k];
        float4 y = pt[lane + 64 * k];
        dot += x.x * y.x + x.y * y.y + x.z * y.z + x.w * y.w;
        ni  += x.x * x.x + x.y * x.y + x.z * x.z + x.w * x.w;
        nt  += y.x * y.x + y.y * y.y + y.z * y.z + y.w * y.w;
      }
#pragma unroll
      for (int off = 32; off; off >>= 1) {
        dot += __shfl_xor(dot, off);
        ni  += __shfl_xor(ni, off);
        nt  += __shfl_xor(nt, off);
      }
      if (lane == 0)
        gscw[a * NB + b] = dot / fmaxf(sqrtf(ni), 1e-12f) / fmaxf(sqrtf(nt), 1e-12f) * 10.0f;
    }
  } else {
    // ---- sorted order (desc by len), deterministic ----
    if (t == 0) {
      int o[32];
      for (int k = 0; k < 32; ++k) o[k] = k;
      for (int x = 0; x < 31; ++x) {
        int best = x;
        for (int y = x + 1; y < 32; ++y)
          if (lenws[o[y]] > lenws[o[best]]) best = y;
        int tmp = o[x]; o[x] = o[best]; o[best] = tmp;
      }
      for (int k = 0; k < 32; ++k) ordws[k] = o[k];
    }
  }
}

// ===================== pair kernel: 8 waves, 2 complementary pairs, 2-dk per barrier =====================
__global__ __launch_bounds__(512, 3) void pair_kernel(
    const _Float16* __restrict__ txf, const _Float16* __restrict__ cTf,
    const _Float16* __restrict__ Gf,
    const float* __restrict__ n1ws, const int* __restrict__ lenws,
    const int* __restrict__ ordws,
    float* __restrict__ simws) {
  const int t = threadIdx.x;
  // XCD swizzle: 512 % 8 == 0 -> bijective
  const int wg = ((blockIdx.x & 7) << 6) + (blockIdx.x >> 3);
  const int j = wg >> 4;
  const int m = wg & 15;
  const int i0 = ordws[m], i1 = ordws[31 - m];   // complementary lens -> ~constant work
  const int len0 = lenws[i0], len1 = lenws[i1];
  const int nlt0 = (len0 + 15) >> 4, nlt1 = (len1 + 15) >> 4;
  const int lane = t & 63, wid = t >> 6;
  const int g = lane >> 4, n16 = lane & 15;
  const bool vb = (wid < 5);   // second S-tile (wid+8 < 13)

  __shared__ __align__(16) union {
    _Float16 e2f[7 * 5 * 64 * 8];          // 35840 B (phases 2-3, per pair sequentially)
    _Float16 b1[2][2][2][5][512];          // 40960 B: [dbuf][dk-in-pair][i][lt][512]
  } U;
  __shared__ float w12s[80], z2s[80], n2s[80];

  const f32x4 z4 = {0.f, 0.f, 0.f, 0.f};
  f32x4 acc[2][2][5];  // [pair][tile][lt] -- all statically indexed
#pragma unroll
  for (int p = 0; p < 2; ++p)
#pragma unroll
    for (int q = 0; q < 2; ++q)
#pragma unroll
      for (int lt = 0; lt < 5; ++lt) acc[p][q][lt] = z4;

  const _Float16* txi0 = txf + (size_t)i0 * 24 * 5 * 512;
  const _Float16* txi1 = txf + (size_t)i1 * 24 * 5 * 512;
  const size_t cj = (size_t)j * 13;
  const int c0 = (wid < 5) ? wid : (wid - 5);   // 5 chunks over 8 waves, 3 dup (benign)

  // ---- prologue: stage dk 0,1 B chunks for both i's (static 4 gloads/wave) ----
  GLOAD16(txi0 + ((size_t)(0 * 5 + c0) << 9) + ((size_t)lane << 3), &U.b1[0][0][0][c0][0]);
  GLOAD16(txi1 + ((size_t)(0 * 5 + c0) << 9) + ((size_t)lane << 3), &U.b1[0][0][1][c0][0]);
  GLOAD16(txi0 + ((size_t)(1 * 5 + c0) << 9) + ((size_t)lane << 3), &U.b1[0][1][0][c0][0]);
  GLOAD16(txi1 + ((size_t)(1 * 5 + c0) << 9) + ((size_t)lane << 3), &U.b1[0][1][1][c0][0]);
  __syncthreads();

  // ---- phase 1: logits for BOTH pairs; 2 dk per barrier iteration ----
#pragma unroll 1
  for (int dkp = 0; dkp < 12; ++dkp) {
    const int cur = dkp & 1;
    const int dk0 = dkp * 2;
    // A-loads first (4 frags: 2 dk x 2 tiles) -> deep MLP, staging doesn't block them
    f16x8 Aa0, Ab0, Aa1, Ab1;
    {
      size_t ao = ((cj + wid) * 24 + dk0) * 512 + ((size_t)lane << 3);
      Aa0 = *(const f16x8*)(cTf + ao);
      Aa1 = *(const f16x8*)(cTf + ao + 512);
    }
    if (vb) {
      size_t ao = ((cj + wid + 8) * 24 + dk0) * 512 + ((size_t)lane << 3);
      Ab0 = *(const f16x8*)(cTf + ao);
      Ab1 = *(const f16x8*)(cTf + ao + 512);
    }
    if (dkp < 11) {
      GLOAD16(txi0 + ((size_t)((dk0 + 2) * 5 + c0) << 9) + ((size_t)lane << 3),
              &U.b1[cur ^ 1][0][0][c0][0]);
      GLOAD16(txi1 + ((size_t)((dk0 + 2) * 5 + c0) << 9) + ((size_t)lane << 3),
              &U.b1[cur ^ 1][0][1][c0][0]);
      GLOAD16(txi0 + ((size_t)((dk0 + 3) * 5 + c0) << 9) + ((size_t)lane << 3),
              &U.b1[cur ^ 1][1][0][c0][0]);
      GLOAD16(txi1 + ((size_t)((dk0 + 3) * 5 + c0) << 9) + ((size_t)lane << 3),
              &U.b1[cur ^ 1][1][1][c0][0]);
    }
    __builtin_amdgcn_s_setprio(1);
#pragma unroll
    for (int lt = 0; lt < 5; ++lt) {
      if (lt < nlt0) {
        f16x8 B0 = *(const f16x8*)&U.b1[cur][0][0][lt][lane << 3];
        acc[0][0][lt] = mfma16(Aa0, B0, acc[0][0][lt]);
        if (vb) acc[0][1][lt] = mfma16(Ab0, B0, acc[0][1][lt]);
      }
      if (lt < nlt1) {
        f16x8 B1 = *(const f16x8*)&U.b1[cur][0][1][lt][lane << 3];
        acc[1][0][lt] = mfma16(Aa0, B1, acc[1][0][lt]);
        if (vb) acc[1][1][lt] = mfma16(Ab0, B1, acc[1][1][lt]);
      }
    }
#pragma unroll
    for (int lt = 0; lt < 5; ++lt) {
      if (lt < nlt0) {
        f16x8 B0 = *(const f16x8*)&U.b1[cur][1][0][lt][lane << 3];
        acc[0][0][lt] = mfma16(Aa1, B0, acc[0][0][lt]);
        if (vb) acc[0][1][lt] = mfma16(Ab1, B0, acc[0][1][lt]);
      }
      if (lt < nlt1) {
        f16x8 B1 = *(const f16x8*)&U.b1[cur][1][1][lt][lane << 3];
        acc[1][0][lt] = mfma16(Aa1, B1, acc[1][0][lt]);
        if (vb) acc[1][1][lt] = mfma16(Ab1, B1, acc[1][1][lt]);
      }
    }
    __builtin_amdgcn_s_setprio(0);
    __syncthreads();
  }

  // ---- phases 2+3+epilogue per pair, sequentially (shared e2f/w12s buffers) ----
#pragma unroll
  for (int p = 0; p < 2; ++p) {
    const int ip   = p ? i1 : i0;
    const int lenp = p ? len1 : len0;
    const int nltp = p ? nlt1 : nlt0;

    __syncthreads();  // protect previous pair's buffers
    if (t < 80) { w12s[t] = 0.f; z2s[t] = 0.f; n2s[t] = 0.f; }
    for (int idx = t; idx < 2240; idx += 512)
      ((uint4*)U.e2f)[idx] = make_uint4(0, 0, 0, 0);
    __syncthreads();

    // ---- phase 2: register softmax over l, e2 = exp(4*a1), fold w12/Z2 ----
    float w12loc[5], z2loc[5];
#pragma unroll
    for (int lt = 0; lt < 5; ++lt) { w12loc[lt] = 0.f; z2loc[lt] = 0.f; }
#pragma unroll
    for (int q = 0; q < 2; ++q) {
      const int S = wid + (q << 3);
      if (q == 0 || vb) {
#pragma unroll
        for (int r = 0; r < 4; ++r) {
          int s = S * 16 + g * 4 + r;
          bool srow = (s < NS);
          float mx = -1e30f;
#pragma unroll
          for (int lt = 0; lt < 5; ++lt) {
            if (lt < nltp) {
              if ((lt * 16 + n16) < lenp) mx = fmaxf(mx, acc[p][q][lt][r]);
            }
          }
          mx = fmaxf(mx, __shfl_xor(mx, 1));
          mx = fmaxf(mx, __shfl_xor(mx, 2));
          mx = fmaxf(mx, __shfl_xor(mx, 4));
          mx = fmaxf(mx, __shfl_xor(mx, 8));
          float z = 0.f;
          float ev[5];
#pragma unroll
          for (int lt = 0; lt < 5; ++lt) {
            float e = 0.f;
            if (lt < nltp) {
              if ((lt * 16 + n16) < lenp) e = __expf(acc[p][q][lt][r] - mx);
            }
            ev[lt] = e;
            z += e;
          }
          z += __shfl_xor(z, 1);
          z += __shfl_xor(z, 2);
          z += __shfl_xor(z, 4);
          z += __shfl_xor(z, 8);
          float inv = 4.0f / z;
#pragma unroll
          for (int lt = 0; lt < 5; ++lt) {
            if (lt < nltp) {
              if (((lt * 16 + n16) < lenp) && srow) {
                float e2 = __expf(ev[lt] * inv);
                w12loc[lt] += e2 * acc[p][q][lt][r];
                z2loc[lt] += e2;
                int kt = s >> 5, kk = s & 31;
                U.e2f[(((kt * 5) + lt) * 64 + (n16 + ((kk >> 3) << 4))) * 8 + (kk & 7)] = (_Float16)e2;
              }
            }
          }
        }
      }
    }
#pragma unroll
    for (int lt = 0; lt < 5; ++lt) {
      w12loc[lt] += __shfl_xor(w12loc[lt], 16);
      w12loc[lt] += __shfl_xor(w12loc[lt], 32);
      z2loc[lt] += __shfl_xor(z2loc[lt], 16);
      z2loc[lt] += __shfl_xor(z2loc[lt], 32);
    }
    if (lane < 16) {
#pragma unroll
      for (int lt = 0; lt < 5; ++lt) {
        if (lt < nltp) {
          atomicAdd(&w12s[lt * 16 + lane], w12loc[lt]);
          atomicAdd(&z2s[lt * 16 + lane], z2loc[lt]);
        }
      }
    }
    __syncthreads();  // e2f complete

    // ---- phase 3: n2^2 = e2^T G e2 via MFMA, single-plane fp16 Gf + kt-prefetch ----
    float n2loc[5];
#pragma unroll
    for (int lt = 0; lt < 5; ++lt) n2loc[lt] = 0.f;
#pragma unroll
    for (int q = 0; q < 2; ++q) {
      const int S = wid + (q << 3);
      if (q == 0 || vb) {
        f32x4 a2[5];
#pragma unroll
        for (int lt = 0; lt < 5; ++lt) a2[lt] = z4;
        const _Float16* gp = Gf + (((size_t)j * 13 + S) * 7) * 512 + ((size_t)lane << 3);
        f16x8 GA = *(const f16x8*)gp;
#pragma unroll
        for (int kt = 0; kt < 7; ++kt) {
          f16x8 GAN;
          if (kt < 6) GAN = *(const f16x8*)(gp + (size_t)(kt + 1) * 512);
          __builtin_amdgcn_s_setprio(1);
#pragma unroll
          for (int lt = 0; lt < 5; ++lt) {
            if (lt < nltp) {
              f16x8 Bv = *(const f16x8*)&U.e2f[(((kt * 5) + lt) * 64 + lane) * 8];
              a2[lt] = mfma16(GA, Bv, a2[lt]);
            }
          }
          __builtin_amdgcn_s_setprio(0);
          if (kt < 6) GA = GAN;
        }
#pragma unroll
        for (int lt = 0; lt < 5; ++lt) {
          if (lt < nltp) {
#pragma unroll
            for (int r = 0; r < 4; ++r) {
              int s = S * 16 + g * 4 + r;
              int kt = s >> 5, kk = s & 31;
              float e2v = (float)U.e2f[(((kt * 5) + lt) * 64 + (n16 + ((kk >> 3) << 4))) * 8 + (kk & 7)];
              n2loc[lt] += e2v * a2[lt][r];
            }
          }
        }
      }
    }
#pragma unroll
    for (int lt = 0; lt < 5; ++lt) {
      n2loc[lt] += __shfl_xor(n2loc[lt], 16);
      n2loc[lt] += __shfl_xor(n2loc[lt], 32);
    }
    if (lane < 16) {
#pragma unroll
      for (int lt = 0; lt < 5; ++lt) {
        if (lt < nltp) atomicAdd(&n2s[lt * 16 + lane], n2loc[lt]);
      }
    }
    __syncthreads();

    // ---- epilogue: cosine + exp, wave-parallel log-sum ----
    if (t < lenp) {
      float z2 = z2s[t];
      float w12v = w12s[t] / z2;
      float n2v = sqrtf(n2s[t]) / z2;
      float n1v = n1ws[ip * 80 + t];
      float cosv = w12v / fmaxf(n1v * n2v, 1e-8f);
      w12s[t] = __expf(5.0f * cosv);
    }
    __syncthreads();
    if (wid == 0) {
      float e = (lane < lenp) ? w12s[lane] : 0.f;
      if (lane + 64 < lenp) e += w12s[lane + 64];
      e += __shfl_xor(e, 1);
      e += __shfl_xor(e, 2);
      e += __shfl_xor(e, 4);
      e += __shfl_xor(e, 8);
      e += __shfl_xor(e, 16);
      e += __shfl_xor(e, 32);
      if (lane == 0) simws[ip * NB + j] = __logf(e);
    }
  }
}

// ===================== final cross-entropies =====================
__global__ void loss_kernel(const float* __restrict__ gscw,
                            const float* __restrict__ simws,
                            float* __restrict__ out) {
  const int t = threadIdx.x;
  __shared__ float gs[NB][NB];
  __shared__ float sl[NB][NB];
  __shared__ float parts[4][NB];
  {
    float4 gv = ((const float4*)gscw)[t];
    ((float4*)gs)[t] = gv;
    float4 v = ((const float4*)simws)[t];
    int ii = t >> 3;
    int j0 = (t & 7) * 4;
    sl[j0 + 0][ii] = v.x * 10.0f;
    sl[j0 + 1][ii] = v.y * 10.0f;
    sl[j0 + 2][ii] = v.z * 10.0f;
    sl[j0 + 3][ii] = v.w * 10.0f;
  }
  __syncthreads();
  if (t < NB) {
    float m, z;
    m = -1e30f;
    for (int c = 0; c < NB; ++c) m = fmaxf(m, gs[t][c]);
    z = 0.f;
    for (int c = 0; c < NB; ++c) z += __expf(gs[t][c] - m);
    parts[0][t] = m + __logf(z) - gs[t][t];

    m = -1e30f;
    for (int c = 0; c < NB; ++c) m = fmaxf(m, gs[c][t]);
    z = 0.f;
    for (int c = 0; c < NB; ++c) z += __expf(gs[c][t] - m);
    parts[1][t] = m + __logf(z) - gs[t][t];

    m = -1e30f;
    for (int c = 0; c < NB; ++c) m = fmaxf(m, sl[t][c]);
    z = 0.f;
    for (int c = 0; c < NB; ++c) z += __expf(sl[t][c] - m);
    parts[2][t] = m + __logf(z) - sl[t][t];

    m = -1e30f;
    for (int c = 0; c < NB; ++c) m = fmaxf(m, sl[c][t]);
    z = 0.f;
    for (int c = 0; c < NB; ++c) z += __expf(sl[c][t] - m);
    parts[3][t] = m + __logf(z) - sl[t][t];
  }
  __syncthreads();
  if (t == 0) {
    float s0 = 0.f, s1 = 0.f, s2 = 0.f, s3 = 0.f;
    for (int r = 0; r < NB; ++r) {
      s0 += parts[0][r]; s1 += parts[1][r];
      s2 += parts[2][r]; s3 += parts[3][r];
    }
    out[0] = 0.5f * (s0 + s1) / 32.0f + 0.5f * (s2 + s3) / 32.0f;
  }
}

extern "C" void kernel_launch(void* const* d_in, const int* in_sizes, int n_in,
                              void* d_out, int out_size, void* d_ws, size_t ws_size,
                              hipStream_t stream) {
  (void)in_sizes; (void)n_in; (void)out_size; (void)ws_size;
  const float* img_global  = (const float*)d_in[0];
  const float* img_local   = (const float*)d_in[1];
  const float* text_global = (const float*)d_in[2];
  const float* text_local  = (const float*)d_in[3];
  const int*   amask       = (const int*)d_in[4];

  _Float16* txf = (_Float16*)d_ws;                // 1,966,080
  _Float16* cTf = txf + (size_t)1966080;          // 5,111,808
  _Float16* Gf  = cTf + (size_t)5111808;          // 1,490,944
  float* fsm  = (float*)(Gf + (size_t)1490944);
  float* n1ws  = fsm;                              // [32][80]
  float* simws = fsm + 2560;                       // [32][32]
  float* gscw  = fsm + 3584;                       // [32][32]
  int*   lenws = (int*)(fsm + 4608);               // [32]
  int*   ordws = (int*)(fsm + 4640);               // [32]

  prep_all_kernel<<<1376, 256, 0, stream>>>(text_local, img_local, amask,
                                            txf, cTf, n1ws, lenws);
  mid_kernel<<<865, 256, 0, stream>>>(cTf, Gf, img_global, text_global,
                                      gscw, lenws, ordws);
  pair_kernel<<<512, 512, 0, stream>>>(txf, cTf, Gf, n1ws, lenws, ordws, simws);
  loss_kernel<<<1, 256, 0, stream>>>(gscw, simws, (float*)d_out);
}